// Round 5
// baseline (349.035 us; speedup 1.0000x reference)
//
#include <hip/hip_runtime.h>

// ChamferLoss: x,y (16,4096,3) f32 -> scalar.
// R5: R4's coop kernel but cg::grid.sync() (measured ~85us EACH in R4:
// VALUBusy 21% x 224us = 47us real work, rest barrier) replaced with a
// flag-array barrier: one flag per block (single writer, release store),
// read-only acquire polling of the 4KB array (no atomic cacheline bouncing),
// s_sleep between polls. Poison 0xAA != magic, so no memset dispatch needed.
// hipLaunchCooperativeKernel retained purely for the co-residency guarantee;
// failure falls back to the R2-proven 4-dispatch atomicMin path.

#define NP 4096
#define NB 16
#define BLK 256
#define NZZ (2 * NB)                  // 32 (dir,b)

// ---- cooperative path config ----
#define RQ 8
#define QCHUNK (NP / (BLK * RQ))      // 2
#define SEG 16
#define DCHUNK (NP / SEG)             // 256
#define NBLOCKS (QCHUNK * NZZ * SEG)  // 1024
#define NQ_TOTAL (NZZ * NP)           // 131072

#define MAGIC1 0x600D0001u
#define MAGIC2 0x600D0002u

__device__ __forceinline__ void flag_barrier(unsigned* __restrict__ flags,
                                             unsigned magic) {
  __syncthreads();                    // all block's prior work done
  if (threadIdx.x == 0) {
    __threadfence();                  // make prior global stores visible
    __hip_atomic_store(&flags[blockIdx.x], magic, __ATOMIC_RELEASE,
                       __HIP_MEMORY_SCOPE_AGENT);
  }
  // poll all NBLOCKS flags; each thread owns NBLOCKS/BLK slots
  for (;;) {
    int ok = 1;
#pragma unroll
    for (int i = 0; i < NBLOCKS / BLK; ++i) {
      const unsigned v = __hip_atomic_load(&flags[i * BLK + threadIdx.x],
                                           __ATOMIC_ACQUIRE,
                                           __HIP_MEMORY_SCOPE_AGENT);
      ok &= (v == magic);
    }
    if (__syncthreads_and(ok)) break;
    __builtin_amdgcn_s_sleep(2);
  }
}

__global__ __launch_bounds__(BLK) void chamfer_all(
    const float* __restrict__ x, const float* __restrict__ y,
    float* __restrict__ ws, float* __restrict__ out) {
  float*    part   = ws;                                   // 8 MB
  float*    bsum   = ws + (size_t)NZZ * SEG * NP;          // 4 KB
  unsigned* flags1 = (unsigned*)(bsum + NBLOCKS);          // 4 KB
  unsigned* flags2 = flags1 + NBLOCKS;                     // 4 KB

  // ---- phase 1: partial mins over one db segment ----
  const int bid = blockIdx.x;
  const int qc  = bid % QCHUNK;
  const int zz  = (bid / QCHUNK) % NZZ;
  const int seg = bid / (QCHUNK * NZZ);
  const int dir = zz >> 4;
  const int b   = zz & 15;

  const float* q_base = (dir == 0 ? x : y) + (size_t)b * NP * 3;
  const float* d_base = (dir == 0 ? y : x) + (size_t)b * NP * 3;

  __shared__ float4 dpt[DCHUNK];
  {
    const int t = threadIdx.x;   // DCHUNK == BLK
    const int i = seg * DCHUNK + t;
    const float dx = d_base[i * 3 + 0];
    const float dy = d_base[i * 3 + 1];
    const float dz = d_base[i * 3 + 2];
    dpt[t] = make_float4(dx, dy, dz, dx * dx + dy * dy + dz * dz);
  }
  __syncthreads();

  float qpx[RQ], qpy[RQ], qpz[RQ], m[RQ];
#pragma unroll
  for (int r = 0; r < RQ; ++r) {
    const int qi = qc * (BLK * RQ) + r * BLK + threadIdx.x;
    qpx[r] = -2.0f * q_base[qi * 3 + 0];
    qpy[r] = -2.0f * q_base[qi * 3 + 1];
    qpz[r] = -2.0f * q_base[qi * 3 + 2];
    m[r]   = 3.4e38f;
  }

#pragma unroll 4
  for (int t = 0; t < DCHUNK; t += 2) {
    const float4 d0 = dpt[t];
    const float4 d1 = dpt[t + 1];
#pragma unroll
    for (int r = 0; r < RQ; ++r) {
      const float v0 = fmaf(d0.x, qpx[r], fmaf(d0.y, qpy[r], fmaf(d0.z, qpz[r], d0.w)));
      const float v1 = fmaf(d1.x, qpx[r], fmaf(d1.y, qpy[r], fmaf(d1.z, qpz[r], d1.w)));
      m[r] = fminf(fminf(v0, v1), m[r]);   // -> v_min3_f32
    }
  }

#pragma unroll
  for (int r = 0; r < RQ; ++r) {
    const int qi = qc * (BLK * RQ) + r * BLK + threadIdx.x;
    part[(size_t)(zz * SEG + seg) * NP + qi] = m[r];
  }

  flag_barrier(flags1, MAGIC1);

  // ---- phase 2: reduce SEG partials, sqrt, per-block sums ----
  __shared__ float wsum[BLK / 64];
  const int g = blockIdx.x * BLK + threadIdx.x;
  float local = 0.0f;
  if (g < NQ_TOTAL) {
    const int zz2 = g >> 12;
    const int qi  = g & (NP - 1);
    const int d2  = zz2 >> 4;
    const int b2  = zz2 & 15;
    const float* qb = (d2 == 0 ? x : y) + (size_t)b2 * NP * 3;

    float mm = part[(size_t)(zz2 * SEG) * NP + qi];
#pragma unroll
    for (int s = 1; s < SEG; ++s)
      mm = fminf(mm, part[(size_t)(zz2 * SEG + s) * NP + qi]);

    const float qx = qb[qi * 3 + 0];
    const float qy = qb[qi * 3 + 1];
    const float qz = qb[qi * 3 + 2];
    const float q2 = qx * qx + qy * qy + qz * qz;
    local = sqrtf(fmaxf(q2 + mm, 0.0f) + 1e-6f) * (1.0f / (float)(NB * NP));
  }
#pragma unroll
  for (int off = 32; off > 0; off >>= 1)
    local += __shfl_down(local, off);
  if ((threadIdx.x & 63) == 0) wsum[threadIdx.x >> 6] = local;
  __syncthreads();
  if (threadIdx.x == 0) {
    float s = 0.0f;
#pragma unroll
    for (int w = 0; w < BLK / 64; ++w) s += wsum[w];
    bsum[blockIdx.x] = s;
  }

  // ---- barrier 2: only block 0 needs to wait ----
  __syncthreads();
  if (threadIdx.x == 0) {
    __threadfence();
    __hip_atomic_store(&flags2[blockIdx.x], MAGIC2, __ATOMIC_RELEASE,
                       __HIP_MEMORY_SCOPE_AGENT);
  }
  if (blockIdx.x != 0) return;

  // block 0: wait for all flags2, then final sum
  for (;;) {
    int ok = 1;
#pragma unroll
    for (int i = 0; i < NBLOCKS / BLK; ++i) {
      const unsigned v = __hip_atomic_load(&flags2[i * BLK + threadIdx.x],
                                           __ATOMIC_ACQUIRE,
                                           __HIP_MEMORY_SCOPE_AGENT);
      ok &= (v == MAGIC2);
    }
    if (__syncthreads_and(ok)) break;
    __builtin_amdgcn_s_sleep(2);
  }

  float s = 0.0f;
#pragma unroll
  for (int i = 0; i < NBLOCKS / BLK; ++i)
    s += bsum[i * BLK + threadIdx.x];
#pragma unroll
  for (int off = 32; off > 0; off >>= 1)
    s += __shfl_down(s, off);
  if ((threadIdx.x & 63) == 0) wsum[threadIdx.x >> 6] = s;
  __syncthreads();
  if (threadIdx.x == 0) {
    float tot = 0.0f;
#pragma unroll
    for (int w = 0; w < BLK / 64; ++w) tot += wsum[w];
    out[0] = tot;
  }
}

// ======== fallback: R2-proven 4-dispatch atomicMin path (<=512KB ws) ========
#define FRQ 4
#define FQCHUNK (NP / (BLK * FRQ))    // 4
#define FSEG 8
#define FDCHUNK (NP / FSEG)           // 512

__device__ __forceinline__ unsigned enc(float f) {
  unsigned u = __float_as_uint(f);
  return (u & 0x80000000u) ? ~u : (u | 0x80000000u);
}
__device__ __forceinline__ float dec(unsigned k) {
  unsigned u = (k & 0x80000000u) ? (k ^ 0x80000000u) : ~k;
  return __uint_as_float(u);
}

__global__ __launch_bounds__(BLK) void chamfer_main(
    const float* __restrict__ x, const float* __restrict__ y,
    unsigned* __restrict__ minkey) {
  const int zz  = blockIdx.y;
  const int dir = zz >> 4;
  const int b   = zz & 15;
  const int seg = blockIdx.z;

  const float* q_base = (dir == 0 ? x : y) + (size_t)b * NP * 3;
  const float* d_base = (dir == 0 ? y : x) + (size_t)b * NP * 3;

  __shared__ float4 dpt[FDCHUNK];
  for (int t = threadIdx.x; t < FDCHUNK; t += BLK) {
    const int i = seg * FDCHUNK + t;
    const float dx = d_base[i * 3 + 0];
    const float dy = d_base[i * 3 + 1];
    const float dz = d_base[i * 3 + 2];
    dpt[t] = make_float4(dx, dy, dz, dx * dx + dy * dy + dz * dz);
  }
  __syncthreads();

  float qpx[FRQ], qpy[FRQ], qpz[FRQ], m[FRQ];
#pragma unroll
  for (int r = 0; r < FRQ; ++r) {
    const int qi = blockIdx.x * (BLK * FRQ) + r * BLK + threadIdx.x;
    qpx[r] = -2.0f * q_base[qi * 3 + 0];
    qpy[r] = -2.0f * q_base[qi * 3 + 1];
    qpz[r] = -2.0f * q_base[qi * 3 + 2];
    m[r]   = 3.4e38f;
  }

#pragma unroll 4
  for (int t = 0; t < FDCHUNK; t += 2) {
    const float4 d0 = dpt[t];
    const float4 d1 = dpt[t + 1];
#pragma unroll
    for (int r = 0; r < FRQ; ++r) {
      const float v0 = fmaf(d0.x, qpx[r], fmaf(d0.y, qpy[r], fmaf(d0.z, qpz[r], d0.w)));
      const float v1 = fmaf(d1.x, qpx[r], fmaf(d1.y, qpy[r], fmaf(d1.z, qpz[r], d1.w)));
      m[r] = fminf(fminf(v0, v1), m[r]);
    }
  }

#pragma unroll
  for (int r = 0; r < FRQ; ++r) {
    const int qi = blockIdx.x * (BLK * FRQ) + r * BLK + threadIdx.x;
    atomicMin(&minkey[(size_t)zz * NP + qi], enc(m[r]));
  }
}

__global__ __launch_bounds__(BLK) void chamfer_finish(
    const float* __restrict__ x, const float* __restrict__ y,
    const unsigned* __restrict__ minkey, float* __restrict__ out) {
  const int g   = blockIdx.x * BLK + threadIdx.x;
  const int zz  = g >> 12;
  const int qi  = g & (NP - 1);
  const int dir = zz >> 4;
  const int b   = zz & 15;
  const float* q_base = (dir == 0 ? x : y) + (size_t)b * NP * 3;

  const float qx = q_base[qi * 3 + 0];
  const float qy = q_base[qi * 3 + 1];
  const float qz = q_base[qi * 3 + 2];
  const float q2 = qx * qx + qy * qy + qz * qz;
  const float m  = dec(minkey[g]);
  float local = sqrtf(fmaxf(q2 + m, 0.0f) + 1e-6f) * (1.0f / (float)(NB * NP));

#pragma unroll
  for (int off = 32; off > 0; off >>= 1)
    local += __shfl_down(local, off);

  __shared__ float wsum2[BLK / 64];
  if ((threadIdx.x & 63) == 0) wsum2[threadIdx.x >> 6] = local;
  __syncthreads();
  if (threadIdx.x == 0) {
    float s = 0.0f;
#pragma unroll
    for (int w = 0; w < BLK / 64; ++w) s += wsum2[w];
    atomicAdd(out, s);
  }
}

extern "C" void kernel_launch(void* const* d_in, const int* in_sizes, int n_in,
                              void* d_out, int out_size, void* d_ws, size_t ws_size,
                              hipStream_t stream) {
  const float* x = (const float*)d_in[0];
  const float* y = (const float*)d_in[1];
  float* out = (float*)d_out;

  const size_t need = ((size_t)NZZ * SEG * NP + 3 * NBLOCKS) * sizeof(float);
  bool coop_done = false;
  if (ws_size >= need) {
    float* ws = (float*)d_ws;
    void* args[] = {(void*)&x, (void*)&y, (void*)&ws, (void*)&out};
    hipError_t e = hipLaunchCooperativeKernel((const void*)chamfer_all,
                                              dim3(NBLOCKS), dim3(BLK),
                                              args, 0, stream);
    coop_done = (e == hipSuccess);
  }

  if (!coop_done) {
    // R2-proven path
    unsigned* minkey = (unsigned*)d_ws;   // NQ_TOTAL uints = 512 KB
    hipMemsetAsync(minkey, 0xFF, (size_t)NQ_TOTAL * sizeof(unsigned), stream);
    hipMemsetAsync(out, 0, sizeof(float), stream);
    dim3 grid(FQCHUNK, NZZ, FSEG);
    chamfer_main<<<grid, BLK, 0, stream>>>(x, y, minkey);
    chamfer_finish<<<NQ_TOTAL / BLK, BLK, 0, stream>>>(x, y, minkey, out);
  }
}

// Round 6
// 176.634 us; speedup vs baseline: 1.9760x; 1.9760x over previous
//
#include <hip/hip_runtime.h>

// ChamferLoss: x,y (16,4096,3) f32 -> scalar.
// R6: grid barriers are ~100us-class on MI355X with 1024 blocks (R4 cg::sync
// ~85us each; R5 flag-array worse) -> last-block-done pattern instead:
// phase-1 blocks write single-writer partial-min slots (no init needed),
// threadfence + atomicAdd(ctr[zz]); the 32nd arriver for each zz reduces that
// zz immediately (agent-scope loads for cross-XCD safety), last zz-finisher
// writes out. No waiting anywhere; finisher work overlaps other blocks'
// phase 1. One tiny init dispatch zeros the 33 counters.

#define NP 4096
#define NB 16
#define BLK 256
#define NZZ (2 * NB)                  // 32 (dir,b)

#define RQ 8
#define QCHUNK (NP / (BLK * RQ))      // 2
#define SEG 16
#define DCHUNK (NP / SEG)             // 256
#define NBLOCKS (QCHUNK * NZZ * SEG)  // 1024
#define ZBLOCKS (QCHUNK * SEG)        // 32 contributors per zz
#define NQ_TOTAL (NZZ * NP)

__global__ void chamfer_init(unsigned* __restrict__ ctr) {
  if (threadIdx.x <= NZZ) ctr[threadIdx.x] = 0u;
}

__global__ __launch_bounds__(BLK) void chamfer_main(
    const float* __restrict__ x, const float* __restrict__ y,
    float* __restrict__ part,        // NZZ*SEG*NP floats (8 MB)
    float* __restrict__ partial,     // NZZ floats
    unsigned* __restrict__ ctr,      // NZZ+1 counters (zeroed by init)
    float* __restrict__ out) {
  const int bid = blockIdx.x;
  const int qc  = bid % QCHUNK;
  const int zz  = (bid / QCHUNK) % NZZ;
  const int seg = bid / (QCHUNK * NZZ);
  const int dir = zz >> 4;
  const int b   = zz & 15;

  const float* q_base = (dir == 0 ? x : y) + (size_t)b * NP * 3;
  const float* d_base = (dir == 0 ? y : x) + (size_t)b * NP * 3;

  // ---- phase 1: partial mins over one db segment ----
  __shared__ float4 dpt[DCHUNK];
  {
    const int t = threadIdx.x;   // DCHUNK == BLK
    const int i = seg * DCHUNK + t;
    const float dx = d_base[i * 3 + 0];
    const float dy = d_base[i * 3 + 1];
    const float dz = d_base[i * 3 + 2];
    dpt[t] = make_float4(dx, dy, dz, dx * dx + dy * dy + dz * dz);
  }
  __syncthreads();

  float qpx[RQ], qpy[RQ], qpz[RQ], m[RQ];
#pragma unroll
  for (int r = 0; r < RQ; ++r) {
    const int qi = qc * (BLK * RQ) + r * BLK + threadIdx.x;
    qpx[r] = -2.0f * q_base[qi * 3 + 0];
    qpy[r] = -2.0f * q_base[qi * 3 + 1];
    qpz[r] = -2.0f * q_base[qi * 3 + 2];
    m[r]   = 3.4e38f;
  }

#pragma unroll 4
  for (int t = 0; t < DCHUNK; t += 2) {
    const float4 d0 = dpt[t];
    const float4 d1 = dpt[t + 1];
#pragma unroll
    for (int r = 0; r < RQ; ++r) {
      const float v0 = fmaf(d0.x, qpx[r], fmaf(d0.y, qpy[r], fmaf(d0.z, qpz[r], d0.w)));
      const float v1 = fmaf(d1.x, qpx[r], fmaf(d1.y, qpy[r], fmaf(d1.z, qpz[r], d1.w)));
      m[r] = fminf(fminf(v0, v1), m[r]);   // -> v_min3_f32
    }
  }

#pragma unroll
  for (int r = 0; r < RQ; ++r) {
    const int qi = qc * (BLK * RQ) + r * BLK + threadIdx.x;
    part[(size_t)(zz * SEG + seg) * NP + qi] = m[r];
  }

  // ---- signal completion; detect last contributor for this zz ----
  __threadfence();                 // every thread: own stores agent-visible
  __syncthreads();
  __shared__ unsigned s_old;
  if (threadIdx.x == 0) s_old = atomicAdd(&ctr[zz], 1u);
  __syncthreads();
  if (s_old != ZBLOCKS - 1) return;

  // ---- zz finisher: reduce SEG partials, sqrt, sum over 4096 queries ----
  float local = 0.0f;
  for (int k = threadIdx.x; k < NP; k += BLK) {
    float mm = 3.4e38f;
#pragma unroll
    for (int s = 0; s < SEG; ++s) {
      const float v = __hip_atomic_load(&part[(size_t)(zz * SEG + s) * NP + k],
                                        __ATOMIC_RELAXED, __HIP_MEMORY_SCOPE_AGENT);
      mm = fminf(mm, v);
    }
    const float qx = q_base[k * 3 + 0];
    const float qy = q_base[k * 3 + 1];
    const float qz = q_base[k * 3 + 2];
    const float q2 = qx * qx + qy * qy + qz * qz;
    local += sqrtf(fmaxf(q2 + mm, 0.0f) + 1e-6f);
  }
  local *= (1.0f / (float)(NB * NP));

#pragma unroll
  for (int off = 32; off > 0; off >>= 1)
    local += __shfl_down(local, off);
  __shared__ float wsum[BLK / 64];
  if ((threadIdx.x & 63) == 0) wsum[threadIdx.x >> 6] = local;
  __syncthreads();

  __shared__ unsigned s_old2;
  if (threadIdx.x == 0) {
    float s = 0.0f;
#pragma unroll
    for (int w = 0; w < BLK / 64; ++w) s += wsum[w];
    partial[zz] = s;
    __threadfence();
    s_old2 = atomicAdd(&ctr[NZZ], 1u);
  }
  __syncthreads();
  if (s_old2 != NZZ - 1) return;

  // ---- final: sum 32 zz partials -> out ----
  float v = 0.0f;
  if (threadIdx.x < NZZ)
    v = __hip_atomic_load(&partial[threadIdx.x],
                          __ATOMIC_RELAXED, __HIP_MEMORY_SCOPE_AGENT);
#pragma unroll
  for (int off = 32; off > 0; off >>= 1)
    v += __shfl_down(v, off);
  if (threadIdx.x == 0) out[0] = v;
}

// ======== fallback: R2-proven 4-dispatch atomicMin path (<=512KB ws) ========
#define FRQ 4
#define FQCHUNK (NP / (BLK * FRQ))    // 4
#define FSEG 8
#define FDCHUNK (NP / FSEG)           // 512

__device__ __forceinline__ unsigned enc(float f) {
  unsigned u = __float_as_uint(f);
  return (u & 0x80000000u) ? ~u : (u | 0x80000000u);
}
__device__ __forceinline__ float dec(unsigned k) {
  unsigned u = (k & 0x80000000u) ? (k ^ 0x80000000u) : ~k;
  return __uint_as_float(u);
}

__global__ __launch_bounds__(BLK) void chamfer_fb_main(
    const float* __restrict__ x, const float* __restrict__ y,
    unsigned* __restrict__ minkey) {
  const int zz  = blockIdx.y;
  const int dir = zz >> 4;
  const int b   = zz & 15;
  const int seg = blockIdx.z;

  const float* q_base = (dir == 0 ? x : y) + (size_t)b * NP * 3;
  const float* d_base = (dir == 0 ? y : x) + (size_t)b * NP * 3;

  __shared__ float4 dpt[FDCHUNK];
  for (int t = threadIdx.x; t < FDCHUNK; t += BLK) {
    const int i = seg * FDCHUNK + t;
    const float dx = d_base[i * 3 + 0];
    const float dy = d_base[i * 3 + 1];
    const float dz = d_base[i * 3 + 2];
    dpt[t] = make_float4(dx, dy, dz, dx * dx + dy * dy + dz * dz);
  }
  __syncthreads();

  float qpx[FRQ], qpy[FRQ], qpz[FRQ], m[FRQ];
#pragma unroll
  for (int r = 0; r < FRQ; ++r) {
    const int qi = blockIdx.x * (BLK * FRQ) + r * BLK + threadIdx.x;
    qpx[r] = -2.0f * q_base[qi * 3 + 0];
    qpy[r] = -2.0f * q_base[qi * 3 + 1];
    qpz[r] = -2.0f * q_base[qi * 3 + 2];
    m[r]   = 3.4e38f;
  }

#pragma unroll 4
  for (int t = 0; t < FDCHUNK; t += 2) {
    const float4 d0 = dpt[t];
    const float4 d1 = dpt[t + 1];
#pragma unroll
    for (int r = 0; r < FRQ; ++r) {
      const float v0 = fmaf(d0.x, qpx[r], fmaf(d0.y, qpy[r], fmaf(d0.z, qpz[r], d0.w)));
      const float v1 = fmaf(d1.x, qpx[r], fmaf(d1.y, qpy[r], fmaf(d1.z, qpz[r], d1.w)));
      m[r] = fminf(fminf(v0, v1), m[r]);
    }
  }

#pragma unroll
  for (int r = 0; r < FRQ; ++r) {
    const int qi = blockIdx.x * (BLK * FRQ) + r * BLK + threadIdx.x;
    atomicMin(&minkey[(size_t)zz * NP + qi], enc(m[r]));
  }
}

__global__ __launch_bounds__(BLK) void chamfer_fb_finish(
    const float* __restrict__ x, const float* __restrict__ y,
    const unsigned* __restrict__ minkey, float* __restrict__ out) {
  const int g   = blockIdx.x * BLK + threadIdx.x;
  const int zz  = g >> 12;
  const int qi  = g & (NP - 1);
  const int dir = zz >> 4;
  const int b   = zz & 15;
  const float* q_base = (dir == 0 ? x : y) + (size_t)b * NP * 3;

  const float qx = q_base[qi * 3 + 0];
  const float qy = q_base[qi * 3 + 1];
  const float qz = q_base[qi * 3 + 2];
  const float q2 = qx * qx + qy * qy + qz * qz;
  const float m  = dec(minkey[g]);
  float local = sqrtf(fmaxf(q2 + m, 0.0f) + 1e-6f) * (1.0f / (float)(NB * NP));

#pragma unroll
  for (int off = 32; off > 0; off >>= 1)
    local += __shfl_down(local, off);

  __shared__ float wsum2[BLK / 64];
  if ((threadIdx.x & 63) == 0) wsum2[threadIdx.x >> 6] = local;
  __syncthreads();
  if (threadIdx.x == 0) {
    float s = 0.0f;
#pragma unroll
    for (int w = 0; w < BLK / 64; ++w) s += wsum2[w];
    atomicAdd(out, s);
  }
}

extern "C" void kernel_launch(void* const* d_in, const int* in_sizes, int n_in,
                              void* d_out, int out_size, void* d_ws, size_t ws_size,
                              hipStream_t stream) {
  const float* x = (const float*)d_in[0];
  const float* y = (const float*)d_in[1];
  float* out = (float*)d_out;

  // ws layout: part (8 MB) | partial[NZZ] | ctr[NZZ+1]
  const size_t part_elems = (size_t)NZZ * SEG * NP;
  const size_t need = (part_elems + NZZ + (NZZ + 1)) * sizeof(float);

  if (ws_size >= need) {
    float*    part    = (float*)d_ws;
    float*    partial = part + part_elems;
    unsigned* ctr     = (unsigned*)(partial + NZZ);

    chamfer_init<<<1, 64, 0, stream>>>(ctr);
    chamfer_main<<<NBLOCKS, BLK, 0, stream>>>(x, y, part, partial, ctr, out);
  } else {
    // R2-proven fallback
    unsigned* minkey = (unsigned*)d_ws;   // NQ_TOTAL uints = 512 KB
    hipMemsetAsync(minkey, 0xFF, (size_t)NQ_TOTAL * sizeof(unsigned), stream);
    hipMemsetAsync(out, 0, sizeof(float), stream);
    dim3 grid(FQCHUNK, NZZ, FSEG);
    chamfer_fb_main<<<grid, BLK, 0, stream>>>(x, y, minkey);
    chamfer_fb_finish<<<NQ_TOTAL / BLK, BLK, 0, stream>>>(x, y, minkey, out);
  }
}

// Round 7
// 102.724 us; speedup vs baseline: 3.3978x; 1.7195x over previous
//
#include <hip/hip_runtime.h>

// ChamferLoss: x,y (16,4096,3) f32 -> scalar.
// R7: kill cross-block bulk data entirely (R4-R6: any scheme that ships the
// 8MB partial-min array across XCDs pays ~80-230us in coherence traffic).
// The db split moves INSIDE the wave: lanes = (td=lane&7, tq=lane>>3);
// td slices the 4096-pt db 8 ways, tq*RQ covers 32 queries/wave; each
// query's min finishes with 3 shfl_xor steps. Only one scalar atomicAdd per
// block leaves the block. Full db staged in LDS as float4(x,y,z,d2)=64KB;
// read pattern dpt[t*8+td] = 8 consecutive float4s x 8-way broadcast = all
// 32 banks, conflict-free. 1024 blocks x 4 waves; 2 blocks/CU (LDS-capped).

#define NP 4096
#define NB 16
#define BLK 256
#define NZZ (2 * NB)            // 32 (dir,b)
#define RQ 4                    // queries per lane
#define QPB 128                 // queries per block (4 waves * 8 tq * RQ)
#define BPZ (NP / QPB)          // 32 blocks per zz
#define NBLOCKS (NZZ * BPZ)     // 1024

__global__ void chamfer_init(float* __restrict__ out) { out[0] = 0.0f; }

__global__ __launch_bounds__(BLK, 2) void chamfer_main(
    const float* __restrict__ x, const float* __restrict__ y,
    float* __restrict__ out) {
  const int bid  = blockIdx.x;
  const int zz   = bid >> 5;          // /BPZ
  const int qblk = bid & (BPZ - 1);
  const int dir  = zz >> 4;
  const int b    = zz & 15;

  const float* q_base = (dir == 0 ? x : y) + (size_t)b * NP * 3;
  const float* d_base = (dir == 0 ? y : x) + (size_t)b * NP * 3;

  // ---- stage full db (4096 pts) into LDS as (x,y,z,d2) ----
  __shared__ float4 dpt[NP];          // 64 KB
  for (int p = threadIdx.x; p < NP; p += BLK) {
    const float dx = d_base[p * 3 + 0];
    const float dy = d_base[p * 3 + 1];
    const float dz = d_base[p * 3 + 2];
    dpt[p] = make_float4(dx, dy, dz, dx * dx + dy * dy + dz * dz);
  }
  __syncthreads();

  const int wid  = threadIdx.x >> 6;  // wave 0..3
  const int lane = threadIdx.x & 63;
  const int td   = lane & 7;          // db slice 0..7
  const int tq   = lane >> 3;         // query group 0..7

  // this lane's RQ queries
  float qpx[RQ], qpy[RQ], qpz[RQ], q2[RQ], m[RQ];
#pragma unroll
  for (int r = 0; r < RQ; ++r) {
    const int qi = qblk * QPB + wid * 32 + tq * RQ + r;
    const float qx = q_base[qi * 3 + 0];
    const float qy = q_base[qi * 3 + 1];
    const float qz = q_base[qi * 3 + 2];
    q2[r]  = qx * qx + qy * qy + qz * qz;
    qpx[r] = -2.0f * qx;
    qpy[r] = -2.0f * qy;
    qpz[r] = -2.0f * qz;
    m[r]   = 3.4e38f;
  }

  // ---- min over this lane's db slice: points t*8+td, t in [0,512) ----
#pragma unroll 4
  for (int t = 0; t < NP / 8; t += 2) {
    const float4 d0 = dpt[t * 8 + td];
    const float4 d1 = dpt[(t + 1) * 8 + td];
#pragma unroll
    for (int r = 0; r < RQ; ++r) {
      const float v0 = fmaf(d0.x, qpx[r], fmaf(d0.y, qpy[r], fmaf(d0.z, qpz[r], d0.w)));
      const float v1 = fmaf(d1.x, qpx[r], fmaf(d1.y, qpy[r], fmaf(d1.z, qpz[r], d1.w)));
      m[r] = fminf(fminf(v0, v1), m[r]);   // -> v_min3_f32
    }
  }

  // ---- reduce mins across the 8 td lanes of each octet ----
#pragma unroll
  for (int r = 0; r < RQ; ++r) {
    m[r] = fminf(m[r], __shfl_xor(m[r], 1));
    m[r] = fminf(m[r], __shfl_xor(m[r], 2));
    m[r] = fminf(m[r], __shfl_xor(m[r], 4));
  }

  // ---- epilogue: sqrt + partial mean (td==0 lanes only) ----
  float local = 0.0f;
  if (td == 0) {
#pragma unroll
    for (int r = 0; r < RQ; ++r)
      local += sqrtf(fmaxf(q2[r] + m[r], 0.0f) + 1e-6f);
    local *= (1.0f / (float)(NB * NP));
  }

  // wave reduce (octet leaders), then block reduce, one atomic per block
#pragma unroll
  for (int off = 32; off > 0; off >>= 1)
    local += __shfl_down(local, off);

  __shared__ float wsum[BLK / 64];
  if (lane == 0) wsum[wid] = local;
  __syncthreads();
  if (threadIdx.x == 0) {
    float s = 0.0f;
#pragma unroll
    for (int w = 0; w < BLK / 64; ++w) s += wsum[w];
    atomicAdd(out, s);
  }
}

extern "C" void kernel_launch(void* const* d_in, const int* in_sizes, int n_in,
                              void* d_out, int out_size, void* d_ws, size_t ws_size,
                              hipStream_t stream) {
  const float* x = (const float*)d_in[0];
  const float* y = (const float*)d_in[1];
  float* out = (float*)d_out;

  chamfer_init<<<1, 64, 0, stream>>>(out);
  chamfer_main<<<NBLOCKS, BLK, 0, stream>>>(x, y, out);
}

// Round 8
// 96.891 us; speedup vs baseline: 3.6023x; 1.0602x over previous
//
#include <hip/hip_runtime.h>

// ChamferLoss: x,y (16,4096,3) f32 -> scalar.
// R8: R7 structure (db split inside wave, no cross-block bulk data) with
// RQ 4->8: each ds_read_b128 now feeds 8 queries' FMAs instead of 4,
// halving LDS-pipe pressure per FLOP (R7: 8 reads per 112 VALU ~ parity
// with VALU pipe; now 8 per 224). NBLOCKS=512 = exactly 2 blocks/CU
// (64KB LDS cap) -> single fully-resident batch, no tail.
// VALU floor: 536.9M pairs x 3.5 ops = 23.9us; target kernel ~28-33us.

#define NP 4096
#define NB 16
#define BLK 256
#define NZZ (2 * NB)            // 32 (dir,b)
#define RQ 8                    // queries per lane
#define QPB 256                 // queries per block (4 waves * 8 tq * RQ)
#define BPZ (NP / QPB)          // 16 blocks per zz
#define NBLOCKS (NZZ * BPZ)     // 512

__global__ void chamfer_init(float* __restrict__ out) { out[0] = 0.0f; }

__global__ __launch_bounds__(BLK, 2) void chamfer_main(
    const float* __restrict__ x, const float* __restrict__ y,
    float* __restrict__ out) {
  const int bid  = blockIdx.x;
  const int zz   = bid >> 4;          // /BPZ
  const int qblk = bid & (BPZ - 1);
  const int dir  = zz >> 4;
  const int b    = zz & 15;

  const float* q_base = (dir == 0 ? x : y) + (size_t)b * NP * 3;
  const float* d_base = (dir == 0 ? y : x) + (size_t)b * NP * 3;

  // ---- stage full db (4096 pts) into LDS as (x,y,z,d2) ----
  __shared__ float4 dpt[NP];          // 64 KB
  for (int p = threadIdx.x; p < NP; p += BLK) {
    const float dx = d_base[p * 3 + 0];
    const float dy = d_base[p * 3 + 1];
    const float dz = d_base[p * 3 + 2];
    dpt[p] = make_float4(dx, dy, dz, dx * dx + dy * dy + dz * dz);
  }
  __syncthreads();

  const int wid  = threadIdx.x >> 6;  // wave 0..3
  const int lane = threadIdx.x & 63;
  const int td   = lane & 7;          // db slice 0..7
  const int tq   = lane >> 3;         // query group 0..7

  // this lane's RQ queries
  float qpx[RQ], qpy[RQ], qpz[RQ], q2[RQ], m[RQ];
#pragma unroll
  for (int r = 0; r < RQ; ++r) {
    const int qi = qblk * QPB + wid * 64 + tq * RQ + r;
    const float qx = q_base[qi * 3 + 0];
    const float qy = q_base[qi * 3 + 1];
    const float qz = q_base[qi * 3 + 2];
    q2[r]  = qx * qx + qy * qy + qz * qz;
    qpx[r] = -2.0f * qx;
    qpy[r] = -2.0f * qy;
    qpz[r] = -2.0f * qz;
    m[r]   = 3.4e38f;
  }

  // ---- min over this lane's db slice: points t*8+td, t in [0,512) ----
#pragma unroll 4
  for (int t = 0; t < NP / 8; t += 2) {
    const float4 d0 = dpt[t * 8 + td];
    const float4 d1 = dpt[(t + 1) * 8 + td];
#pragma unroll
    for (int r = 0; r < RQ; ++r) {
      const float v0 = fmaf(d0.x, qpx[r], fmaf(d0.y, qpy[r], fmaf(d0.z, qpz[r], d0.w)));
      const float v1 = fmaf(d1.x, qpx[r], fmaf(d1.y, qpy[r], fmaf(d1.z, qpz[r], d1.w)));
      m[r] = fminf(fminf(v0, v1), m[r]);   // -> v_min3_f32
    }
  }

  // ---- reduce mins across the 8 td lanes of each octet ----
#pragma unroll
  for (int r = 0; r < RQ; ++r) {
    m[r] = fminf(m[r], __shfl_xor(m[r], 1));
    m[r] = fminf(m[r], __shfl_xor(m[r], 2));
    m[r] = fminf(m[r], __shfl_xor(m[r], 4));
  }

  // ---- epilogue: sqrt + partial mean (td==0 lanes only) ----
  float local = 0.0f;
  if (td == 0) {
#pragma unroll
    for (int r = 0; r < RQ; ++r)
      local += sqrtf(fmaxf(q2[r] + m[r], 0.0f) + 1e-6f);
    local *= (1.0f / (float)(NB * NP));
  }

  // wave reduce (octet leaders), then block reduce, one atomic per block
#pragma unroll
  for (int off = 32; off > 0; off >>= 1)
    local += __shfl_down(local, off);

  __shared__ float wsum[BLK / 64];
  if (lane == 0) wsum[wid] = local;
  __syncthreads();
  if (threadIdx.x == 0) {
    float s = 0.0f;
#pragma unroll
    for (int w = 0; w < BLK / 64; ++w) s += wsum[w];
    atomicAdd(out, s);
  }
}

extern "C" void kernel_launch(void* const* d_in, const int* in_sizes, int n_in,
                              void* d_out, int out_size, void* d_ws, size_t ws_size,
                              hipStream_t stream) {
  const float* x = (const float*)d_in[0];
  const float* y = (const float*)d_in[1];
  float* out = (float*)d_out;

  chamfer_init<<<1, 64, 0, stream>>>(out);
  chamfer_main<<<NBLOCKS, BLK, 0, stream>>>(x, y, out);
}